// Round 3
// baseline (198.434 us; speedup 1.0000x reference)
//
#include <hip/hip_runtime.h>

#define BS 64
#define TT 2048
#define NJ 24
#define ROWF 99            // 24*4 quats + 3 pos
#define BLOCK 256
#define RPB (BLOCK / 2)    // 128 rows per block, 2 threads per row (X-side / Y-side)
#define NROWS (BS * TT)    // 131072 rows

// 16B load at 4B alignment (rows are 396B-strided). gfx950 handles dword-aligned
// dwordx4 in HW (may split lines).
__device__ __forceinline__ void ld4u(const float* __restrict__ p, float* q) {
  const float4 v = *reinterpret_cast<const float4*>(p);
  q[0] = v.x; q[1] = v.y; q[2] = v.z; q[3] = v.w;
}

__device__ __forceinline__ void quat2mat_s(const float* q, float s, float* R) {
  const float w = q[0], x = q[1], y = q[2], z = q[3];
  const float xx = s*x*x, yy = s*y*y, zz = s*z*z;
  const float xy = s*x*y, xz = s*x*z, yz = s*y*z;
  const float xw = s*x*w, yw = s*y*w, zw = s*z*w;
  R[0] = 1.0f - (yy+zz); R[1] = xy - zw;        R[2] = xz + yw;
  R[3] = xy + zw;        R[4] = 1.0f - (xx+zz); R[5] = yz - xw;
  R[6] = xz - yw;        R[7] = yz + xw;        R[8] = 1.0f - (xx+yy);
}

__device__ __forceinline__ void mm3(const float* A, const float* B, float* C) {
#pragma unroll
  for (int r = 0; r < 3; ++r) {
#pragma unroll
    for (int c = 0; c < 3; ++c) {
      C[3*r+c] = fmaf(A[3*r], B[c], fmaf(A[3*r+1], B[3+c], A[3*r+2]*B[6+c]));
    }
  }
}

// Decomposition: 2 threads per row. Even lane runs the X chain, odd lane the Y
// chain (halved dependency chain + 2x wave count vs one-thread-per-row).
// All coupling terms (rot diff, gtr diff, pos diff) are squared -> sign-free, so
// both lanes fetch the partner's values via __shfl_xor(..,1) and accumulate the
// same diff^2; final constants carry a 0.5.
// FK slots: topology[i] < i and index-order liveness shows <=3 live ancestor
// states -> 3 register slots. Each lane carries its own G (3x3) and gtr (3) per slot.
__global__ __launch_bounds__(BLOCK, 4) void motion_loss_kernel(
    const float* __restrict__ Ym, const float* __restrict__ Xm,
    const float* __restrict__ Yt, const float* __restrict__ Xt,
    float* __restrict__ out) {
  __shared__ float ts[2][NJ * 3];   // 576 B: t-vectors for this block's batch

  const int tid = threadIdx.x;
  const int side = tid & 1;                                  // 0 = X, 1 = Y
  const size_t row = (size_t)blockIdx.x * RPB + (tid >> 1);  // block stays in one batch
  const int b = (int)(((size_t)blockIdx.x * RPB) / TT);      // uniform per block

  if (tid < NJ * 3)                        ts[0][tid]       = Xt[(size_t)b * NJ * 3 + tid];
  else if (tid >= 128 && tid < 128 + NJ*3) ts[1][tid - 128] = Yt[(size_t)b * NJ * 3 + (tid - 128)];
  __syncthreads();

  const float* __restrict__ mr = (side ? Ym : Xm) + row * ROWF;
  const float* __restrict__ tv = ts[side];

  float G[3][9], gtr[3][3];
  float rot_acc = 0.0f, gtr_acc = 0.0f, pos_acc = 0.0f;

  // ---- joint 0 (root) ----
  {
    float q[4]; ld4u(mr, q);
    const float qq = q[0]*q[0] + q[1]*q[1] + q[2]*q[2] + q[3]*q[3];
    const float in = 1.0f / fmaxf(sqrtf(qq), 1e-12f);
    const float n0 = q[0]*in, n1 = q[1]*in, n2 = q[2]*in, n3 = q[3]*in;
    const float r0 = n0 - __shfl_xor(n0, 1, 64);
    const float r1 = n1 - __shfl_xor(n1, 1, 64);
    const float r2 = n2 - __shfl_xor(n2, 1, 64);
    const float r3 = n3 - __shfl_xor(n3, 1, 64);
    rot_acc += r0*r0 + r1*r1 + r2*r2 + r3*r3;
    quat2mat_s(q, 2.0f / qq, G[0]);
    float p[4]; ld4u(mr + 95, p);     // floats [95..98]; pos = [96..98]
    gtr[0][0] = p[1]; gtr[0][1] = p[2]; gtr[0][2] = p[3];
    const float d0 = gtr[0][0] - __shfl_xor(gtr[0][0], 1, 64);
    const float d1 = gtr[0][1] - __shfl_xor(gtr[0][1], 1, 64);
    const float d2 = gtr[0][2] - __shfl_xor(gtr[0][2], 1, 64);
    const float dd = d0*d0 + d1*d1 + d2*d2;
    gtr_acc += dd;                    // root contributes to gtr MSE
    pos_acc  = dd;                    // and to the pos MSE
  }

#define JSTEP(j, PS, NS) do {                                                  \
    float q[4]; ld4u(mr + 4*(j), q);                                           \
    const float qq = q[0]*q[0] + q[1]*q[1] + q[2]*q[2] + q[3]*q[3];            \
    const float in = 1.0f / fmaxf(sqrtf(qq), 1e-12f);                          \
    const float n0 = q[0]*in, n1 = q[1]*in, n2 = q[2]*in, n3 = q[3]*in;        \
    const float r0 = n0 - __shfl_xor(n0, 1, 64);                               \
    const float r1 = n1 - __shfl_xor(n1, 1, 64);                               \
    const float r2 = n2 - __shfl_xor(n2, 1, 64);                               \
    const float r3 = n3 - __shfl_xor(n3, 1, 64);                               \
    rot_acc += r0*r0 + r1*r1 + r2*r2 + r3*r3;                                  \
    const float t0 = tv[3*(j)], t1 = tv[3*(j)+1], t2 = tv[3*(j)+2];            \
    const float v0 = fmaf(G[PS][0],t0, fmaf(G[PS][1],t1, fmaf(G[PS][2],t2, gtr[PS][0]))); \
    const float v1 = fmaf(G[PS][3],t0, fmaf(G[PS][4],t1, fmaf(G[PS][5],t2, gtr[PS][1]))); \
    const float v2 = fmaf(G[PS][6],t0, fmaf(G[PS][7],t1, fmaf(G[PS][8],t2, gtr[PS][2]))); \
    const float d0 = v0 - __shfl_xor(v0, 1, 64);                               \
    const float d1 = v1 - __shfl_xor(v1, 1, 64);                               \
    const float d2 = v2 - __shfl_xor(v2, 1, 64);                               \
    gtr_acc += d0*d0 + d1*d1 + d2*d2;                                          \
    float R[9], Gn[9];                                                         \
    quat2mat_s(q, 2.0f / qq, R);                                               \
    mm3(G[PS], R, Gn);                                                         \
    _Pragma("unroll")                                                          \
    for (int k = 0; k < 9; ++k) G[NS][k] = Gn[k];                              \
    gtr[NS][0] = v0; gtr[NS][1] = v1; gtr[NS][2] = v2;                         \
  } while (0)

  // Index-order walk of TOPOLOGY = [-1,0,0,0,1,2,3,4,5,6,7,8,9,9,9,12,13,14,16,17,18,19,20,21]
  JSTEP( 1, 0, 1);  // p=0
  JSTEP( 2, 0, 2);  // p=0
  JSTEP( 3, 0, 0);  // p=0 (last child of 0)
  JSTEP( 4, 1, 1);  // p=1
  JSTEP( 5, 2, 2);  // p=2
  JSTEP( 6, 0, 0);  // p=3
  JSTEP( 7, 1, 1);  // p=4
  JSTEP( 8, 2, 2);  // p=5
  JSTEP( 9, 0, 0);  // p=6
  JSTEP(10, 1, 1);  // p=7 (leaf)
  JSTEP(11, 2, 2);  // p=8 (leaf)
  JSTEP(12, 0, 1);  // p=9, slot B free
  JSTEP(13, 0, 2);  // p=9, slot C free
  JSTEP(14, 0, 0);  // p=9 (last child of 9)
  JSTEP(15, 1, 1);  // p=12 (leaf)
  JSTEP(16, 2, 2);  // p=13
  JSTEP(17, 0, 0);  // p=14
  JSTEP(18, 2, 2);  // p=16
  JSTEP(19, 0, 0);  // p=17
  JSTEP(20, 2, 2);  // p=18
  JSTEP(21, 0, 0);  // p=19
  JSTEP(22, 2, 2);  // p=20 (leaf)
  JSTEP(23, 0, 0);  // p=21 (leaf)
#undef JSTEP

  // Both lanes of a pair accumulate identical diff^2 -> constants carry 0.5.
  const float c_rot = 0.5f / ((float)NROWS * NJ * 4);   // B1 * mean over (bs,T,24,4)
  const float c_gtr = 1.25f / ((float)NROWS * NJ * 3);  // B2 * 2.5 * mean * 0.5
  const float c_pos = 0.5f / ((float)NROWS * 3);        // B2 * mean * 0.5
  float contrib = c_rot * rot_acc + c_gtr * gtr_acc + c_pos * pos_acc;
#pragma unroll
  for (int o = 32; o > 0; o >>= 1) contrib += __shfl_down(contrib, o, 64);
  if ((tid & 63) == 0) atomicAdd(out, contrib);
}

extern "C" void kernel_launch(void* const* d_in, const int* in_sizes, int n_in,
                              void* d_out, int out_size, void* d_ws, size_t ws_size,
                              hipStream_t stream) {
  const float* Ym = (const float*)d_in[0];
  const float* Xm = (const float*)d_in[1];
  const float* Yt = (const float*)d_in[2];
  const float* Xt = (const float*)d_in[3];
  float* out = (float*)d_out;
  hipMemsetAsync(out, 0, sizeof(float), stream);  // graph-capturable
  motion_loss_kernel<<<NROWS / RPB, BLOCK, 0, stream>>>(Ym, Xm, Yt, Xt, out);
}